// Round 8
// baseline (281.837 us; speedup 1.0000x reference)
//
#include <hip/hip_runtime.h>
#include <hip/hip_bf16.h>

typedef __hip_bfloat16 bf16;
typedef __attribute__((ext_vector_type(8))) short short8;
typedef __attribute__((ext_vector_type(4))) float f32x4;
typedef __attribute__((ext_vector_type(16))) float f32x16;

#define B_SZ 32
#define N_SZ 512
#define L_SZ 1024
#define D_SZ 512
#define H_SZ 8

__device__ __forceinline__ void gload16(void* lds, const void* g) {
    typedef const __attribute__((address_space(1))) unsigned int* gp_t;
    typedef __attribute__((address_space(3))) unsigned int* lp_t;
    __builtin_amdgcn_global_load_lds((gp_t)g, (lp_t)lds, 16, 0, 0);
}

__device__ __forceinline__ unsigned int cvtpk(float lo, float hi) {
    unsigned int r;
    asm("v_cvt_pk_bf16_f32 %0, %1, %2" : "=v"(r) : "v"(lo), "v"(hi));
    return r;
}

__device__ __forceinline__ float fexp2(float x) {
    float r;
    asm("v_exp_f32 %0, %1" : "=v"(r) : "v"(x));
    return r;
}

// barrier that drains LDS ops but leaves global loads in flight (no vmcnt drain)
__device__ __forceinline__ void bar_lgkm() {
    asm volatile("s_waitcnt lgkmcnt(0)" ::: "memory");
    __builtin_amdgcn_s_barrier();
    asm volatile("" ::: "memory");
}

// ---------------- f32 -> bf16 convert (both inputs, one dispatch) ----------------
struct alignas(8) B4 { bf16 a, b, c, d; };

__global__ void cvt_all(const float* __restrict__ xq, const float* __restrict__ xkv,
                        bf16* __restrict__ dq, bf16* __restrict__ dkv) {
    int i = blockIdx.x * 256 + threadIdx.x;
    const float* s;
    bf16* d;
    if (i < 2097152) {
        s = xq; d = dq;
    } else {
        i -= 2097152; s = xkv; d = dkv;
    }
    float4 v = ((const float4*)s)[i];
    B4 o;
    o.a = __float2bfloat16(v.x);
    o.b = __float2bfloat16(v.y);
    o.c = __float2bfloat16(v.z);
    o.d = __float2bfloat16(v.w);
    *(B4*)(d + (size_t)i * 4) = o;
}

// ---------------- 512x512 transpose + convert: Wt[e][d] = bf16(W[d][e]) ----------------
__global__ void tpose4(const float* __restrict__ s0, const float* __restrict__ s1,
                       const float* __restrict__ s2, const float* __restrict__ s3,
                       bf16* __restrict__ d0, bf16* __restrict__ d1,
                       bf16* __restrict__ d2, bf16* __restrict__ d3) {
    __shared__ float t[32][33];
    const float* s = blockIdx.z == 0 ? s0 : blockIdx.z == 1 ? s1 : blockIdx.z == 2 ? s2 : s3;
    bf16* d = blockIdx.z == 0 ? d0 : blockIdx.z == 1 ? d1 : blockIdx.z == 2 ? d2 : d3;
    int tx = threadIdx.x, ty = threadIdx.y;  // 32 x 8
    int r0 = blockIdx.y * 32, c0 = blockIdx.x * 32;
#pragma unroll
    for (int i = 0; i < 32; i += 8)
        t[ty + i][tx] = s[(size_t)(r0 + ty + i) * 512 + c0 + tx];
    __syncthreads();
#pragma unroll
    for (int i = 0; i < 32; i += 8)
        d[(size_t)(c0 + ty + i) * 512 + r0 + tx] = __float2bfloat16(t[tx][ty + i]);
}

// ---------------- fused QKV projection: reg-staged pipeline, 32KB LDS ----------------
// mode 0: Q = xq * WqT^T -> qh [b][h][n][c]
// mode 1: K = xkv * WkT^T + rpb -> kh [b][h][l][c]
// mode 2: V^T = WvT * xkv^T -> vTh [b][h][c][l]
__global__ __launch_bounds__(256, 4) void gemm_qkv(
    const bf16* __restrict__ xq, const bf16* __restrict__ xkv,
    const bf16* __restrict__ WqT, const bf16* __restrict__ WkT,
    const bf16* __restrict__ WvT, const float* __restrict__ rpb,
    bf16* __restrict__ qh, bf16* __restrict__ kh, bf16* __restrict__ vTh) {
    __shared__ char sm[32768];  // [A 16KB | B 16KB], single tile; reused by epilogue
    const int tid = threadIdx.x;
    const int wave = tid >> 6, lane = tid & 63;
    const int wr = wave >> 1, wc = wave & 1;
    const int g16 = lane >> 4, r16 = lane & 15;

    // bijective XCD swizzle: 2560 = 8 * 320
    const int orig = blockIdx.x;
    const int bid = (orig & 7) * 320 + (orig >> 3);

    int mode;
    long rowBase;
    int colBase;
    const bf16 *A, *Bt;
    if (bid < 512) {
        mode = 0; A = xq; Bt = WqT;
        rowBase = (long)(bid >> 2) * 128; colBase = (bid & 3) * 128;
    } else if (bid < 1536) {
        mode = 1; int t = bid - 512; A = xkv; Bt = WkT;
        rowBase = (long)(t >> 2) * 128; colBase = (t & 3) * 128;
    } else {
        mode = 2; int t = bid - 1536; A = WvT; Bt = xkv;
        rowBase = (long)(t & 3) * 128; colBase = (t >> 2) * 128;
    }

    // staging addresses: pre-swizzled global source, linear LDS dest (rule 21 pair)
    const int row_ = tid >> 3;
    const int gj_ = ((tid & 7) ^ (row_ & 7)) * 8;
    const bf16* aSrc = A + (rowBase + row_) * 512 + gj_;
    const bf16* bSrc = Bt + ((long)colBase + row_) * 512 + gj_;

    f32x4 acc[4][4];
#pragma unroll
    for (int m = 0; m < 4; ++m)
#pragma unroll
        for (int n = 0; n < 4; ++n) acc[m][n] = {0.f, 0.f, 0.f, 0.f};

    uint4 ra[4], rb[4];
    // load tile 0 to regs
#pragma unroll
    for (int r = 0; r < 4; ++r) {
        ra[r] = *(const uint4*)(aSrc + r * 16384);
        rb[r] = *(const uint4*)(bSrc + r * 16384);
    }
    // write tile 0 to LDS (compiler inserts counted vmcnt before first use)
#pragma unroll
    for (int r = 0; r < 4; ++r) {
        *(uint4*)&sm[r * 4096 + tid * 16] = ra[r];
        *(uint4*)&sm[16384 + r * 4096 + tid * 16] = rb[r];
    }
    // issue tile 1 loads (stay in flight across the barrier)
#pragma unroll
    for (int r = 0; r < 4; ++r) {
        ra[r] = *(const uint4*)(aSrc + r * 16384 + 64);
        rb[r] = *(const uint4*)(bSrc + r * 16384 + 64);
    }
    bar_lgkm();  // tile 0 visible to all waves; global loads NOT drained

    for (int t = 0; t < 8; ++t) {
#pragma unroll
        for (int kk = 0; kk < 2; ++kk) {
            short8 a[4], b[4];
#pragma unroll
            for (int m = 0; m < 4; ++m) {
                int row = wr * 64 + m * 16 + r16;
                a[m] = *(const short8*)(&sm[row * 128 + (((kk * 4 + g16) ^ (row & 7)) * 16)]);
            }
#pragma unroll
            for (int n = 0; n < 4; ++n) {
                int row = wc * 64 + n * 16 + r16;
                b[n] = *(const short8*)(
                    &sm[16384 + row * 128 + (((kk * 4 + g16) ^ (row & 7)) * 16)]);
            }
#pragma unroll
            for (int m = 0; m < 4; ++m)
#pragma unroll
                for (int n = 0; n < 4; ++n)
                    acc[m][n] =
                        __builtin_amdgcn_mfma_f32_16x16x32_bf16(a[m], b[n], acc[m][n], 0, 0, 0);
        }
        if (t < 7) {
            bar_lgkm();  // all waves done reading tile t
#pragma unroll
            for (int r = 0; r < 4; ++r) {
                *(uint4*)&sm[r * 4096 + tid * 16] = ra[r];
                *(uint4*)&sm[16384 + r * 4096 + tid * 16] = rb[r];
            }
            if (t < 6) {
                const int nk = (t + 2) * 64;
#pragma unroll
                for (int r = 0; r < 4; ++r) {
                    ra[r] = *(const uint4*)(aSrc + r * 16384 + nk);
                    rb[r] = *(const uint4*)(bSrc + r * 16384 + nk);
                }
            }
            bar_lgkm();  // tile t+1 visible
        }
    }

    __syncthreads();  // all tile-7 reads done before epilogue overwrites LDS

    // ---------- epilogue: two passes of 32 rows through 8KB/wave LDS ----------
    float* ep = (float*)(sm + wave * 8192);  // 32 x 64 f32
    const long gm0 = rowBase + wr * 64;
    const int e0 = colBase + wc * 64;
    bf16* obase;
    int rstride;
    int s0g = 0;
    if (mode == 2) {
        int hh = (int)gm0 >> 6;
        int bb = e0 >> 10, s0 = e0 & 1023;
        obase = vTh + (((long)bb * H_SZ + hh) * 64 + ((int)gm0 & 63)) * (long)L_SZ + s0;
        rstride = L_SZ;
    } else if (mode == 1) {
        int bb = (int)(gm0 >> 10), s0 = (int)gm0 & 1023;
        int hh = e0 >> 6;
        obase = kh + (((long)bb * H_SZ + hh) * (long)L_SZ + s0) * 64 + (e0 & 63);
        rstride = 64;
        s0g = (int)gm0 & 1023;
    } else {
        int bb = (int)(gm0 >> 9), s0 = (int)gm0 & 511;
        int hh = e0 >> 6;
        obase = qh + (((long)bb * H_SZ + hh) * (long)N_SZ + s0) * 64 + (e0 & 63);
        rstride = 64;
    }

#pragma unroll
    for (int half = 0; half < 2; ++half) {
#pragma unroll
        for (int dm = 0; dm < 2; ++dm) {
            int m = half * 2 + dm;
#pragma unroll
            for (int n = 0; n < 4; ++n)
#pragma unroll
                for (int r = 0; r < 4; ++r)
                    ep[(dm * 16 + g16 * 4 + r) * 64 + n * 16 + r16] = acc[m][n][r];
        }
#pragma unroll
        for (int i = 0; i < 4; ++i) {
            int chunk = i * 64 + lane;            // 0..255
            int lr = chunk >> 3, cc = chunk & 7;  // local row 0..31, 16B-chunk
            float4 fa = *(float4*)(ep + lr * 64 + cc * 8);
            float4 fb = *(float4*)(ep + lr * 64 + cc * 8 + 4);
            int grow = half * 32 + lr;
            if (mode == 1) {
                const float* rp = rpb + (long)(s0g + grow) * 512 + e0 + cc * 8;
                float4 rra = *(const float4*)rp;
                float4 rrb = *(const float4*)(rp + 4);
                fa.x += rra.x; fa.y += rra.y; fa.z += rra.z; fa.w += rra.w;
                fb.x += rrb.x; fb.y += rrb.y; fb.z += rrb.z; fb.w += rrb.w;
            }
            uint4 st;
            st.x = cvtpk(fa.x, fa.y);
            st.y = cvtpk(fa.z, fa.w);
            st.z = cvtpk(fb.x, fb.y);
            st.w = cvtpk(fb.z, fb.w);
            *(uint4*)(obase + (long)grow * rstride + cc * 8) = st;
        }
        asm volatile("" ::: "memory");  // keep pass 0 reads before pass 1 overwrites
    }
}

// ---------------- O projection: reg-staged pipeline, f32 out + bo ----------------
__global__ __launch_bounds__(256, 4) void gemm_o(const bf16* __restrict__ A,
                                                 const bf16* __restrict__ Bt,
                                                 float* __restrict__ outp,
                                                 const float* __restrict__ bias) {
    __shared__ char sm[32768];
    const int tid = threadIdx.x;
    const int wave = tid >> 6, lane = tid & 63;
    const int wr = wave >> 1, wc = wave & 1;
    const int g16 = lane >> 4, r16 = lane & 15;

    const int orig = blockIdx.x;  // 512 = 8 * 64
    const int bid = (orig & 7) * 64 + (orig >> 3);
    const long rowBase = (long)(bid >> 2) * 128;
    const int colBase = (bid & 3) * 128;

    const int row_ = tid >> 3;
    const int gj_ = ((tid & 7) ^ (row_ & 7)) * 8;
    const bf16* aSrc = A + (rowBase + row_) * 512 + gj_;
    const bf16* bSrc = Bt + ((long)colBase + row_) * 512 + gj_;

    f32x4 acc[4][4];
#pragma unroll
    for (int m = 0; m < 4; ++m)
#pragma unroll
        for (int n = 0; n < 4; ++n) acc[m][n] = {0.f, 0.f, 0.f, 0.f};

    uint4 ra[4], rb[4];
#pragma unroll
    for (int r = 0; r < 4; ++r) {
        ra[r] = *(const uint4*)(aSrc + r * 16384);
        rb[r] = *(const uint4*)(bSrc + r * 16384);
    }
#pragma unroll
    for (int r = 0; r < 4; ++r) {
        *(uint4*)&sm[r * 4096 + tid * 16] = ra[r];
        *(uint4*)&sm[16384 + r * 4096 + tid * 16] = rb[r];
    }
#pragma unroll
    for (int r = 0; r < 4; ++r) {
        ra[r] = *(const uint4*)(aSrc + r * 16384 + 64);
        rb[r] = *(const uint4*)(bSrc + r * 16384 + 64);
    }
    bar_lgkm();

    for (int t = 0; t < 8; ++t) {
#pragma unroll
        for (int kk = 0; kk < 2; ++kk) {
            short8 a[4], b[4];
#pragma unroll
            for (int m = 0; m < 4; ++m) {
                int row = wr * 64 + m * 16 + r16;
                a[m] = *(const short8*)(&sm[row * 128 + (((kk * 4 + g16) ^ (row & 7)) * 16)]);
            }
#pragma unroll
            for (int n = 0; n < 4; ++n) {
                int row = wc * 64 + n * 16 + r16;
                b[n] = *(const short8*)(
                    &sm[16384 + row * 128 + (((kk * 4 + g16) ^ (row & 7)) * 16)]);
            }
#pragma unroll
            for (int m = 0; m < 4; ++m)
#pragma unroll
                for (int n = 0; n < 4; ++n)
                    acc[m][n] =
                        __builtin_amdgcn_mfma_f32_16x16x32_bf16(a[m], b[n], acc[m][n], 0, 0, 0);
        }
        if (t < 7) {
            bar_lgkm();
#pragma unroll
            for (int r = 0; r < 4; ++r) {
                *(uint4*)&sm[r * 4096 + tid * 16] = ra[r];
                *(uint4*)&sm[16384 + r * 4096 + tid * 16] = rb[r];
            }
            if (t < 6) {
                const int nk = (t + 2) * 64;
#pragma unroll
                for (int r = 0; r < 4; ++r) {
                    ra[r] = *(const uint4*)(aSrc + r * 16384 + nk);
                    rb[r] = *(const uint4*)(bSrc + r * 16384 + nk);
                }
            }
            bar_lgkm();
        }
    }

#pragma unroll
    for (int m = 0; m < 4; ++m) {
#pragma unroll
        for (int r = 0; r < 4; ++r) {
            long gm = rowBase + wr * 64 + m * 16 + g16 * 4 + r;
#pragma unroll
            for (int n = 0; n < 4; ++n) {
                int e = colBase + wc * 64 + n * 16 + r16;
                outp[gm * 512 + e] = acc[m][n][r] + bias[e];
            }
        }
    }
}

// ---------------- flash attention: KVBLK=64, swapped QK^T, in-register softmax ----
__global__ __launch_bounds__(512, 4) void attn256(const bf16* __restrict__ q,
                                                  const bf16* __restrict__ k,
                                                  const bf16* __restrict__ vT,
                                                  const int* __restrict__ mask,
                                                  bf16* __restrict__ o) {
    __shared__ bf16 lK[2][64 * 64];   // [k 64][c 64], row slots xor-swizzled by (k&7)
    __shared__ bf16 lV[2][64 * 64];   // [c 64][k 64], row slots xor-swizzled by (c&7)
    __shared__ float lMf[1024];       // mask -> {0, -1e38}

    const int tid = threadIdx.x;
    const int wv = tid >> 6, lane = tid & 63;
    const int q32 = lane & 31, hi = lane >> 5;

    const int wg = blockIdx.x;
    const int xcd = wg & 7, slot = wg >> 3;
    const int bh = xcd * 32 + (slot >> 1), qc = slot & 1;
    const int b = bh >> 3, h = bh & 7;

    const bf16* kbase = k + (long)bh * L_SZ * 64;
    const bf16* vbase = vT + (long)bh * 64 * L_SZ;

    const int* mrow = mask + b * L_SZ;
    lMf[tid] = mrow[tid] ? -1e38f : 0.f;
    lMf[tid + 512] = mrow[tid + 512] ? -1e38f : 0.f;

    const int r_ = tid >> 3, j_ = tid & 7;
    const int gj_ = (j_ ^ (r_ & 7)) * 8;
    const bf16* gK = kbase + r_ * 64 + gj_;           // +4096 per tile
    const bf16* gV = vbase + (long)r_ * L_SZ + gj_;   // +64 per tile
    char* dK0 = (char*)(&lK[0][0]) + tid * 16;
    char* dK1 = (char*)(&lK[1][0]) + tid * 16;
    char* dV0 = (char*)(&lV[0][0]) + tid * 16;
    char* dV1 = (char*)(&lV[1][0]) + tid * 16;
    gload16(dK0, gK);
    gload16(dV0, gV);

    const bf16* qp = q + ((long)bh * N_SZ + qc * 256 + wv * 32 + q32) * 64 + hi * 8;
    short8 qf[4];
#pragma unroll
    for (int t = 0; t < 4; ++t) qf[t] = *(const short8*)(qp + t * 16);

    float mrun = 0.f, lrun = 0.f;
    f32x16 oa0, oa1;
#pragma unroll
    for (int i = 0; i < 16; ++i) { oa0[i] = 0.f; oa1[i] = 0.f; }

    __syncthreads();

    const float CL = 0.18033688011112042f;  // SCALE * log2(e)

    for (int kb = 0; kb < 16; ++kb) {
        const char* curK = (const char*)(&lK[kb & 1][0]);
        const char* curV = (const char*)(&lV[kb & 1][0]);
        if (kb < 15) {
            gload16((kb & 1) ? dK0 : dK1, gK + (kb + 1) * 4096);
            gload16((kb & 1) ? dV0 : dV1, gV + (kb + 1) * 64);
        }

        // S^T: two independent chains (k rows 0-31 and 32-63)
        f32x16 sA, sB;
#pragma unroll
        for (int i = 0; i < 16; ++i) { sA[i] = 0.f; sB[i] = 0.f; }
#pragma unroll
        for (int t = 0; t < 4; ++t) {
            int sl = ((t * 2 + hi) ^ (q32 & 7)) * 16;
            short8 kfA = *(const short8*)(curK + q32 * 128 + sl);
            short8 kfB = *(const short8*)(curK + (32 + q32) * 128 + sl);
            sA = __builtin_amdgcn_mfma_f32_32x32x16_bf16(kfA, qf[t], sA, 0, 0, 0);
            sB = __builtin_amdgcn_mfma_f32_32x32x16_bf16(kfB, qf[t], sB, 0, 0, 0);
        }

        // mask bias: sA reg i -> k_local = (i&3) + 8*(i>>2) + 4*hi; sB: +32
        const float* mf = lMf + kb * 64 + hi * 4;
        float4 ma0 = *(const float4*)(mf);
        float4 ma1 = *(const float4*)(mf + 8);
        float4 ma2 = *(const float4*)(mf + 16);
        float4 ma3 = *(const float4*)(mf + 24);
        float4 mb0 = *(const float4*)(mf + 32);
        float4 mb1 = *(const float4*)(mf + 40);
        float4 mb2 = *(const float4*)(mf + 48);
        float4 mb3 = *(const float4*)(mf + 56);
        float mba[16] = {ma0.x, ma0.y, ma0.z, ma0.w, ma1.x, ma1.y, ma1.z, ma1.w,
                         ma2.x, ma2.y, ma2.z, ma2.w, ma3.x, ma3.y, ma3.z, ma3.w};
        float mbb[16] = {mb0.x, mb0.y, mb0.z, mb0.w, mb1.x, mb1.y, mb1.z, mb1.w,
                         mb2.x, mb2.y, mb2.z, mb2.w, mb3.x, mb3.y, mb3.z, mb3.w};

        float t32[32];
#pragma unroll
        for (int i = 0; i < 16; ++i) {
            t32[i] = fmaf(sA[i], CL, mba[i]);
            t32[16 + i] = fmaf(sB[i], CL, mbb[i]);
        }

        // tile max over 64 k
        float m16[16];
#pragma unroll
        for (int i = 0; i < 16; ++i) m16[i] = fmaxf(t32[i], t32[16 + i]);
        float m8[8];
#pragma unroll
        for (int i = 0; i < 8; ++i) m8[i] = fmaxf(m16[i], m16[i + 8]);
        float tm = fmaxf(fmaxf(fmaxf(m8[0], m8[4]), fmaxf(m8[1], m8[5])),
                         fmaxf(fmaxf(m8[2], m8[6]), fmaxf(m8[3], m8[7])));
        tm = fmaxf(tm, __shfl_xor(tm, 32));

        // defer-max (T13)
        if (__any(tm > mrun + 8.f)) {
            float mnew = fmaxf(mrun, tm);
            float al = fexp2(mrun - mnew);
            mrun = mnew;
            lrun *= al;
#pragma unroll
            for (int i = 0; i < 16; ++i) { oa0[i] *= al; oa1[i] *= al; }
        }

#pragma unroll
        for (int i = 0; i < 32; ++i) t32[i] = fexp2(t32[i] - mrun);
        float s16[16];
#pragma unroll
        for (int i = 0; i < 16; ++i) s16[i] = t32[i] + t32[16 + i];
        float s8[8];
#pragma unroll
        for (int i = 0; i < 8; ++i) s8[i] = s16[i] + s16[i + 8];
        float ps = ((s8[0] + s8[4]) + (s8[1] + s8[5])) + ((s8[2] + s8[6]) + (s8[3] + s8[7]));
        ps += __shfl_xor(ps, 32);
        lrun += ps;

        // P -> 4 bf16 B-fragments via cvt_pk + permlane32_swap
        union U { unsigned int u[4]; short8 s8v; };
        U fr[4];
#pragma unroll
        for (int fkt = 0; fkt < 4; ++fkt) {
            const float* tp = t32 + fkt * 8;
            unsigned int y0 = cvtpk(tp[0], tp[1]);
            unsigned int y1 = cvtpk(tp[2], tp[3]);
            unsigned int y2 = cvtpk(tp[4], tp[5]);
            unsigned int y3 = cvtpk(tp[6], tp[7]);
            asm("v_permlane32_swap_b32 %0, %1" : "+v"(y0), "+v"(y2));
            asm("v_permlane32_swap_b32 %0, %1" : "+v"(y1), "+v"(y3));
            fr[fkt].u[0] = y0; fr[fkt].u[1] = y1; fr[fkt].u[2] = y2; fr[fkt].u[3] = y3;
        }

        // O^T += V^T . P^T  (2 c-tiles x 4 k-quarters)
#pragma unroll
        for (int kt = 0; kt < 4; ++kt) {
            int sw = ((kt * 2 + hi) ^ (q32 & 7)) * 16;
            short8 v0 = *(const short8*)(curV + q32 * 128 + sw);
            short8 v1 = *(const short8*)(curV + (32 + q32) * 128 + sw);
            oa0 = __builtin_amdgcn_mfma_f32_32x32x16_bf16(v0, fr[kt].s8v, oa0, 0, 0, 0);
            oa1 = __builtin_amdgcn_mfma_f32_32x32x16_bf16(v1, fr[kt].s8v, oa1, 0, 0, 0);
        }

        __syncthreads();
    }

    // epilogue: O^T[c][q] -> o[b][q][h*64 + c]
    float inv = 1.f / lrun;
    bf16* op = o + ((long)b * N_SZ + qc * 256 + wv * 32 + q32) * 512 + h * 64;
#pragma unroll
    for (int ct = 0; ct < 2; ++ct) {
#pragma unroll
        for (int rq = 0; rq < 4; ++rq) {
            int c0 = ct * 32 + rq * 8 + hi * 4;
            float v0 = (ct ? oa1[rq * 4 + 0] : oa0[rq * 4 + 0]) * inv;
            float v1 = (ct ? oa1[rq * 4 + 1] : oa0[rq * 4 + 1]) * inv;
            float v2 = (ct ? oa1[rq * 4 + 2] : oa0[rq * 4 + 2]) * inv;
            float v3 = (ct ? oa1[rq * 4 + 3] : oa0[rq * 4 + 3]) * inv;
            uint2 st;
            st.x = cvtpk(v0, v1);
            st.y = cvtpk(v2, v3);
            *(uint2*)(op + c0) = st;
        }
    }
}

extern "C" void kernel_launch(void* const* d_in, const int* in_sizes, int n_in,
                              void* d_out, int out_size, void* d_ws, size_t ws_size,
                              hipStream_t stream) {
    const float* x_q  = (const float*)d_in[0];
    const float* x_kv = (const float*)d_in[1];
    const int*   mask = (const int*)d_in[2];
    const float* Wq   = (const float*)d_in[3];
    const float* Wk   = (const float*)d_in[4];
    const float* Wv   = (const float*)d_in[5];
    const float* Wo   = (const float*)d_in[6];
    const float* bo   = (const float*)d_in[7];
    const float* rpb  = (const float*)d_in[8];
    float* out = (float*)d_out;

    char* w = (char*)d_ws;
    bf16* xq_bf  = (bf16*)(w + 0);           // reused as o_bf after attention
    bf16* xkv_bf = (bf16*)(w + 16777216);
    bf16* WqT    = (bf16*)(w + 50331648);
    bf16* WkT    = WqT + 262144;
    bf16* WvT    = WkT + 262144;
    bf16* WoT    = WvT + 262144;
    bf16* qh     = (bf16*)(w + 52428800);    // [b][h][n][c]
    bf16* kh     = (bf16*)(w + 69206016);    // [b][h][l][c]
    bf16* vTh    = (bf16*)(w + 102760448);   // [b][h][c][l]
    bf16* o_bf   = xq_bf;

    cvt_all<<<24576, 256, 0, stream>>>(x_q, x_kv, xq_bf, xkv_bf);
    tpose4<<<dim3(16, 16, 4), dim3(32, 8), 0, stream>>>(Wq, Wk, Wv, Wo, WqT, WkT, WvT, WoT);

    gemm_qkv<<<2560, 256, 0, stream>>>(xq_bf, xkv_bf, WqT, WkT, WvT, rpb, qh, kh, vTh);

    attn256<<<512, 512, 0, stream>>>(qh, kh, vTh, mask, o_bf);

    gemm_o<<<512, 256, 0, stream>>>(o_bf, WoT, out, bo);
}

// Round 9
// 162.184 us; speedup vs baseline: 1.7378x; 1.7378x over previous
//
#include <hip/hip_runtime.h>
#include <hip/hip_bf16.h>

typedef __hip_bfloat16 bf16;
typedef __attribute__((ext_vector_type(8))) short short8;
typedef __attribute__((ext_vector_type(4))) float f32x4;
typedef __attribute__((ext_vector_type(16))) float f32x16;

#define B_SZ 32
#define N_SZ 512
#define L_SZ 1024
#define D_SZ 512
#define H_SZ 8

__device__ __forceinline__ void gload16(void* lds, const void* g) {
    typedef const __attribute__((address_space(1))) unsigned int* gp_t;
    typedef __attribute__((address_space(3))) unsigned int* lp_t;
    __builtin_amdgcn_global_load_lds((gp_t)g, (lp_t)lds, 16, 0, 0);
}

__device__ __forceinline__ unsigned int cvtpk(float lo, float hi) {
    unsigned int r;
    asm("v_cvt_pk_bf16_f32 %0, %1, %2" : "=v"(r) : "v"(lo), "v"(hi));
    return r;
}

__device__ __forceinline__ float fexp2(float x) {
    float r;
    asm("v_exp_f32 %0, %1" : "=v"(r) : "v"(x));
    return r;
}

// ---------------- prep: f32->bf16 convert (blocks 0-24575) + weight transpose ----------
struct alignas(8) B4 { bf16 a, b, c, d; };

__global__ __launch_bounds__(256) void prep(
    const float* __restrict__ xq, const float* __restrict__ xkv,
    bf16* __restrict__ dq, bf16* __restrict__ dkv,
    const float* __restrict__ s0, const float* __restrict__ s1,
    const float* __restrict__ s2, const float* __restrict__ s3,
    bf16* __restrict__ d0, bf16* __restrict__ d1,
    bf16* __restrict__ d2, bf16* __restrict__ d3) {
    __shared__ float t[32][33];
    const int tid = threadIdx.x;
    int bid = blockIdx.x;
    if (bid < 24576) {
        int i = bid * 256 + tid;
        const float* s;
        bf16* d;
        if (i < 2097152) {
            s = xq; d = dq;
        } else {
            i -= 2097152; s = xkv; d = dkv;
        }
        float4 v = ((const float4*)s)[i];
        B4 o;
        o.a = __float2bfloat16(v.x);
        o.b = __float2bfloat16(v.y);
        o.c = __float2bfloat16(v.z);
        o.d = __float2bfloat16(v.w);
        *(B4*)(d + (size_t)i * 4) = o;
    } else {
        int tb = bid - 24576;  // 0..1023
        int bz = tb & 3, rem = tb >> 2;
        int by = rem & 15, bx = rem >> 4;
        const float* s = bz == 0 ? s0 : bz == 1 ? s1 : bz == 2 ? s2 : s3;
        bf16* d = bz == 0 ? d0 : bz == 1 ? d1 : bz == 2 ? d2 : d3;
        int tx = tid & 31, ty = tid >> 5;  // 32 x 8
        int r0 = by * 32, c0 = bx * 32;
#pragma unroll
        for (int i = 0; i < 32; i += 8)
            t[ty + i][tx] = s[(size_t)(r0 + ty + i) * 512 + c0 + tx];
        __syncthreads();
#pragma unroll
        for (int i = 0; i < 32; i += 8)
            d[(size_t)(c0 + ty + i) * 512 + r0 + tx] = __float2bfloat16(t[tx][ty + i]);
    }
}

// ---------------- fused QKV projection: 2560 blocks, gload_lds dbuf pipeline ----------
// mode 0: Q = xq * WqT^T -> qh [b][h][n][c]
// mode 1: K = xkv * WkT^T + rpb -> kh [b][h][l][c]
// mode 2: V^T = WvT * xkv^T -> vTh [b][h][c][l]
__global__ __launch_bounds__(256) void gemm_qkv(
    const bf16* __restrict__ xq, const bf16* __restrict__ xkv,
    const bf16* __restrict__ WqT, const bf16* __restrict__ WkT,
    const bf16* __restrict__ WvT, const float* __restrict__ rpb,
    bf16* __restrict__ qh, bf16* __restrict__ kh, bf16* __restrict__ vTh) {
    __shared__ char sm[2][32768];  // [buf][A 16KB | B 16KB]; reused by epilogue
    const int tid = threadIdx.x;
    const int wave = tid >> 6, lane = tid & 63;
    const int wr = wave >> 1, wc = wave & 1;
    const int g16 = lane >> 4, r16 = lane & 15;

    // bijective XCD swizzle: 2560 = 8 * 320
    const int orig = blockIdx.x;
    const int bid = (orig & 7) * 320 + (orig >> 3);

    int mode;
    long rowBase;
    int colBase;
    const bf16 *A, *Bt;
    if (bid < 512) {
        mode = 0; A = xq; Bt = WqT;
        rowBase = (long)(bid >> 2) * 128; colBase = (bid & 3) * 128;
    } else if (bid < 1536) {
        mode = 1; int t = bid - 512; A = xkv; Bt = WkT;
        rowBase = (long)(t >> 2) * 128; colBase = (t & 3) * 128;
    } else {
        mode = 2; int t = bid - 1536; A = WvT; Bt = xkv;
        rowBase = (long)(t & 3) * 128; colBase = (t >> 2) * 128;
    }

    // loop-invariant staging addresses (pre-swizzled source, linear LDS dest)
    const int row_ = tid >> 3;
    const int gj_ = ((tid & 7) ^ (row_ & 7)) * 8;
    const bf16* aSrc = A + (rowBase + row_) * 512 + gj_;
    const bf16* bSrc = Bt + ((long)colBase + row_) * 512 + gj_;

    f32x4 acc[4][4];
#pragma unroll
    for (int m = 0; m < 4; ++m)
#pragma unroll
        for (int n = 0; n < 4; ++n) acc[m][n] = {0.f, 0.f, 0.f, 0.f};

    // prologue: stage K-tile 0 into buf 0
#pragma unroll
    for (int rnd = 0; rnd < 4; ++rnd) {
        gload16(&sm[0][rnd * 4096 + tid * 16], aSrc + rnd * 16384);
        gload16(&sm[0][16384 + rnd * 4096 + tid * 16], bSrc + rnd * 16384);
    }
    __syncthreads();

    for (int t = 0; t < 8; ++t) {
        const int cur = t & 1;
        if (t < 7) {
            const int nk = (t + 1) * 64;
#pragma unroll
            for (int rnd = 0; rnd < 4; ++rnd) {
                gload16(&sm[cur ^ 1][rnd * 4096 + tid * 16], aSrc + rnd * 16384 + nk);
                gload16(&sm[cur ^ 1][16384 + rnd * 4096 + tid * 16], bSrc + rnd * 16384 + nk);
            }
        }
        const char* lA = &sm[cur][0];
        const char* lB = &sm[cur][16384];
#pragma unroll
        for (int kk = 0; kk < 2; ++kk) {
            short8 a[4], b[4];
#pragma unroll
            for (int m = 0; m < 4; ++m) {
                int row = wr * 64 + m * 16 + r16;
                a[m] = *(const short8*)(lA + row * 128 + (((kk * 4 + g16) ^ (row & 7)) * 16));
            }
#pragma unroll
            for (int n = 0; n < 4; ++n) {
                int row = wc * 64 + n * 16 + r16;
                b[n] = *(const short8*)(lB + row * 128 + (((kk * 4 + g16) ^ (row & 7)) * 16));
            }
#pragma unroll
            for (int m = 0; m < 4; ++m)
#pragma unroll
                for (int n = 0; n < 4; ++n)
                    acc[m][n] =
                        __builtin_amdgcn_mfma_f32_16x16x32_bf16(a[m], b[n], acc[m][n], 0, 0, 0);
        }
        __syncthreads();
    }

    __syncthreads();  // all waves done with tile 7 before epilogue reuses LDS

    // ---------- epilogue: stage f32 tile in per-wave LDS, store coalesced 16B ----------
    float* ep = (float*)((char*)sm + wave * 16384);  // 64 x 64 f32 = 16KB
#pragma unroll
    for (int m = 0; m < 4; ++m)
#pragma unroll
        for (int n = 0; n < 4; ++n)
#pragma unroll
            for (int r = 0; r < 4; ++r)
                ep[(m * 16 + g16 * 4 + r) * 64 + n * 16 + r16] = acc[m][n][r];

    const long gm0 = rowBase + wr * 64;  // first row of wave tile (mult. of 64)
    const int e0 = colBase + wc * 64;    // first col (mult. of 64)
    bf16* obase;
    int rstride;
    int s0g = 0;
    if (mode == 2) {
        int hh = (int)gm0 >> 6;
        int bb = e0 >> 10, s0 = e0 & 1023;
        obase = vTh + (((long)bb * H_SZ + hh) * 64 + ((int)gm0 & 63)) * (long)L_SZ + s0;
        rstride = L_SZ;
    } else if (mode == 1) {
        int bb = (int)(gm0 >> 10), s0 = (int)gm0 & 1023;
        int hh = e0 >> 6;
        obase = kh + (((long)bb * H_SZ + hh) * (long)L_SZ + s0) * 64 + (e0 & 63);
        rstride = 64;
        s0g = (int)gm0 & 1023;
    } else {
        int bb = (int)(gm0 >> 9), s0 = (int)gm0 & 511;
        int hh = e0 >> 6;
        obase = qh + (((long)bb * H_SZ + hh) * (long)N_SZ + s0) * 64 + (e0 & 63);
        rstride = 64;
    }

#pragma unroll
    for (int i = 0; i < 8; ++i) {
        int chunk = i * 64 + lane;            // 0..511
        int lr = chunk >> 3, cc = chunk & 7;  // row, 16B-chunk within row
        float4 fa = *(float4*)(ep + lr * 64 + cc * 8);
        float4 fb = *(float4*)(ep + lr * 64 + cc * 8 + 4);
        if (mode == 1) {
            const float* rp = rpb + (long)(s0g + lr) * 512 + e0 + cc * 8;
            float4 ra = *(const float4*)rp;
            float4 rb = *(const float4*)(rp + 4);
            fa.x += ra.x; fa.y += ra.y; fa.z += ra.z; fa.w += ra.w;
            fb.x += rb.x; fb.y += rb.y; fb.z += rb.z; fb.w += rb.w;
        }
        uint4 st;
        st.x = cvtpk(fa.x, fa.y);
        st.y = cvtpk(fa.z, fa.w);
        st.z = cvtpk(fb.x, fb.y);
        st.w = cvtpk(fb.z, fb.w);
        *(uint4*)(obase + (long)lr * rstride + cc * 8) = st;
    }
}

// ---------------- O projection: gload_lds dbuf pipeline, f32 out + bo ----------------
__global__ __launch_bounds__(256) void gemm_o(const bf16* __restrict__ A,
                                              const bf16* __restrict__ Bt,
                                              float* __restrict__ outp,
                                              const float* __restrict__ bias) {
    __shared__ char sm[2][32768];
    const int tid = threadIdx.x;
    const int wave = tid >> 6, lane = tid & 63;
    const int wr = wave >> 1, wc = wave & 1;
    const int g16 = lane >> 4, r16 = lane & 15;

    const int orig = blockIdx.x;  // 512 = 8 * 64
    const int bid = (orig & 7) * 64 + (orig >> 3);
    const long rowBase = (long)(bid >> 2) * 128;
    const int colBase = (bid & 3) * 128;

    const int row_ = tid >> 3;
    const int gj_ = ((tid & 7) ^ (row_ & 7)) * 8;
    const bf16* aSrc = A + (rowBase + row_) * 512 + gj_;
    const bf16* bSrc = Bt + ((long)colBase + row_) * 512 + gj_;

    f32x4 acc[4][4];
#pragma unroll
    for (int m = 0; m < 4; ++m)
#pragma unroll
        for (int n = 0; n < 4; ++n) acc[m][n] = {0.f, 0.f, 0.f, 0.f};

#pragma unroll
    for (int rnd = 0; rnd < 4; ++rnd) {
        gload16(&sm[0][rnd * 4096 + tid * 16], aSrc + rnd * 16384);
        gload16(&sm[0][16384 + rnd * 4096 + tid * 16], bSrc + rnd * 16384);
    }
    __syncthreads();

    for (int t = 0; t < 8; ++t) {
        const int cur = t & 1;
        if (t < 7) {
            const int nk = (t + 1) * 64;
#pragma unroll
            for (int rnd = 0; rnd < 4; ++rnd) {
                gload16(&sm[cur ^ 1][rnd * 4096 + tid * 16], aSrc + rnd * 16384 + nk);
                gload16(&sm[cur ^ 1][16384 + rnd * 4096 + tid * 16], bSrc + rnd * 16384 + nk);
            }
        }
        const char* lA = &sm[cur][0];
        const char* lB = &sm[cur][16384];
#pragma unroll
        for (int kk = 0; kk < 2; ++kk) {
            short8 a[4], b[4];
#pragma unroll
            for (int m = 0; m < 4; ++m) {
                int row = wr * 64 + m * 16 + r16;
                a[m] = *(const short8*)(lA + row * 128 + (((kk * 4 + g16) ^ (row & 7)) * 16));
            }
#pragma unroll
            for (int n = 0; n < 4; ++n) {
                int row = wc * 64 + n * 16 + r16;
                b[n] = *(const short8*)(lB + row * 128 + (((kk * 4 + g16) ^ (row & 7)) * 16));
            }
#pragma unroll
            for (int m = 0; m < 4; ++m)
#pragma unroll
                for (int n = 0; n < 4; ++n)
                    acc[m][n] =
                        __builtin_amdgcn_mfma_f32_16x16x32_bf16(a[m], b[n], acc[m][n], 0, 0, 0);
        }
        __syncthreads();
    }

#pragma unroll
    for (int m = 0; m < 4; ++m) {
#pragma unroll
        for (int r = 0; r < 4; ++r) {
            long gm = rowBase + wr * 64 + m * 16 + g16 * 4 + r;
#pragma unroll
            for (int n = 0; n < 4; ++n) {
                int e = colBase + wc * 64 + n * 16 + r16;
                outp[gm * 512 + e] = acc[m][n][r] + bias[e];
            }
        }
    }
}

// ---------------- flash attention: KVBLK=64, swapped QK^T, in-register softmax ----
__global__ __launch_bounds__(512, 4) void attn256(const bf16* __restrict__ q,
                                                  const bf16* __restrict__ k,
                                                  const bf16* __restrict__ vT,
                                                  const int* __restrict__ mask,
                                                  bf16* __restrict__ o) {
    __shared__ bf16 lK[2][64 * 64];   // [k 64][c 64], row slots xor-swizzled by (k&7)
    __shared__ bf16 lV[2][64 * 64];   // [c 64][k 64], row slots xor-swizzled by (c&7)
    __shared__ float lMf[1024];       // mask -> {0, -1e38}

    const int tid = threadIdx.x;
    const int wv = tid >> 6, lane = tid & 63;
    const int q32 = lane & 31, hi = lane >> 5;

    const int wg = blockIdx.x;
    const int xcd = wg & 7, slot = wg >> 3;
    const int bh = xcd * 32 + (slot >> 1), qc = slot & 1;
    const int b = bh >> 3, h = bh & 7;

    const bf16* kbase = k + (long)bh * L_SZ * 64;
    const bf16* vbase = vT + (long)bh * 64 * L_SZ;

    const int* mrow = mask + b * L_SZ;
    lMf[tid] = mrow[tid] ? -1e38f : 0.f;
    lMf[tid + 512] = mrow[tid + 512] ? -1e38f : 0.f;

    const int r_ = tid >> 3, j_ = tid & 7;
    const int gj_ = (j_ ^ (r_ & 7)) * 8;
    const bf16* gK = kbase + r_ * 64 + gj_;           // +4096 per tile
    const bf16* gV = vbase + (long)r_ * L_SZ + gj_;   // +64 per tile
    char* dK0 = (char*)(&lK[0][0]) + tid * 16;
    char* dK1 = (char*)(&lK[1][0]) + tid * 16;
    char* dV0 = (char*)(&lV[0][0]) + tid * 16;
    char* dV1 = (char*)(&lV[1][0]) + tid * 16;
    gload16(dK0, gK);
    gload16(dV0, gV);

    const bf16* qp = q + ((long)bh * N_SZ + qc * 256 + wv * 32 + q32) * 64 + hi * 8;
    short8 qf[4];
#pragma unroll
    for (int t = 0; t < 4; ++t) qf[t] = *(const short8*)(qp + t * 16);

    float mrun = 0.f, lrun = 0.f;
    f32x16 oa0, oa1;
#pragma unroll
    for (int i = 0; i < 16; ++i) { oa0[i] = 0.f; oa1[i] = 0.f; }

    __syncthreads();

    const float CL = 0.18033688011112042f;  // SCALE * log2(e)

    for (int kb = 0; kb < 16; ++kb) {
        const char* curK = (const char*)(&lK[kb & 1][0]);
        const char* curV = (const char*)(&lV[kb & 1][0]);
        if (kb < 15) {
            gload16((kb & 1) ? dK0 : dK1, gK + (kb + 1) * 4096);
            gload16((kb & 1) ? dV0 : dV1, gV + (kb + 1) * 64);
        }

        // S^T: two independent chains (k rows 0-31 and 32-63)
        f32x16 sA, sB;
#pragma unroll
        for (int i = 0; i < 16; ++i) { sA[i] = 0.f; sB[i] = 0.f; }
#pragma unroll
        for (int t = 0; t < 4; ++t) {
            int sl = ((t * 2 + hi) ^ (q32 & 7)) * 16;
            short8 kfA = *(const short8*)(curK + q32 * 128 + sl);
            short8 kfB = *(const short8*)(curK + (32 + q32) * 128 + sl);
            sA = __builtin_amdgcn_mfma_f32_32x32x16_bf16(kfA, qf[t], sA, 0, 0, 0);
            sB = __builtin_amdgcn_mfma_f32_32x32x16_bf16(kfB, qf[t], sB, 0, 0, 0);
        }

        // mask bias: sA reg i -> k_local = (i&3) + 8*(i>>2) + 4*hi; sB: +32
        const float* mf = lMf + kb * 64 + hi * 4;
        float4 ma0 = *(const float4*)(mf);
        float4 ma1 = *(const float4*)(mf + 8);
        float4 ma2 = *(const float4*)(mf + 16);
        float4 ma3 = *(const float4*)(mf + 24);
        float4 mb0 = *(const float4*)(mf + 32);
        float4 mb1 = *(const float4*)(mf + 40);
        float4 mb2 = *(const float4*)(mf + 48);
        float4 mb3 = *(const float4*)(mf + 56);
        float mba[16] = {ma0.x, ma0.y, ma0.z, ma0.w, ma1.x, ma1.y, ma1.z, ma1.w,
                         ma2.x, ma2.y, ma2.z, ma2.w, ma3.x, ma3.y, ma3.z, ma3.w};
        float mbb[16] = {mb0.x, mb0.y, mb0.z, mb0.w, mb1.x, mb1.y, mb1.z, mb1.w,
                         mb2.x, mb2.y, mb2.z, mb2.w, mb3.x, mb3.y, mb3.z, mb3.w};

        float t32[32];
#pragma unroll
        for (int i = 0; i < 16; ++i) {
            t32[i] = fmaf(sA[i], CL, mba[i]);
            t32[16 + i] = fmaf(sB[i], CL, mbb[i]);
        }

        // tile max over 64 k
        float m16[16];
#pragma unroll
        for (int i = 0; i < 16; ++i) m16[i] = fmaxf(t32[i], t32[16 + i]);
        float m8[8];
#pragma unroll
        for (int i = 0; i < 8; ++i) m8[i] = fmaxf(m16[i], m16[i + 8]);
        float tm = fmaxf(fmaxf(fmaxf(m8[0], m8[4]), fmaxf(m8[1], m8[5])),
                         fmaxf(fmaxf(m8[2], m8[6]), fmaxf(m8[3], m8[7])));
        tm = fmaxf(tm, __shfl_xor(tm, 32));

        // defer-max (T13)
        if (__any(tm > mrun + 8.f)) {
            float mnew = fmaxf(mrun, tm);
            float al = fexp2(mrun - mnew);
            mrun = mnew;
            lrun *= al;
#pragma unroll
            for (int i = 0; i < 16; ++i) { oa0[i] *= al; oa1[i] *= al; }
        }

#pragma unroll
        for (int i = 0; i < 32; ++i) t32[i] = fexp2(t32[i] - mrun);
        float s16[16];
#pragma unroll
        for (int i = 0; i < 16; ++i) s16[i] = t32[i] + t32[16 + i];
        float s8[8];
#pragma unroll
        for (int i = 0; i < 8; ++i) s8[i] = s16[i] + s16[i + 8];
        float ps = ((s8[0] + s8[4]) + (s8[1] + s8[5])) + ((s8[2] + s8[6]) + (s8[3] + s8[7]));
        ps += __shfl_xor(ps, 32);
        lrun += ps;

        // P -> 4 bf16 B-fragments via cvt_pk + permlane32_swap
        union U { unsigned int u[4]; short8 s8v; };
        U fr[4];
#pragma unroll
        for (int fkt = 0; fkt < 4; ++fkt) {
            const float* tp = t32 + fkt * 8;
            unsigned int y0 = cvtpk(tp[0], tp[1]);
            unsigned int y1 = cvtpk(tp[2], tp[3]);
            unsigned int y2 = cvtpk(tp[4], tp[5]);
            unsigned int y3 = cvtpk(tp[6], tp[7]);
            asm("v_permlane32_swap_b32 %0, %1" : "+v"(y0), "+v"(y2));
            asm("v_permlane32_swap_b32 %0, %1" : "+v"(y1), "+v"(y3));
            fr[fkt].u[0] = y0; fr[fkt].u[1] = y1; fr[fkt].u[2] = y2; fr[fkt].u[3] = y3;
        }

        // O^T += V^T . P^T  (2 c-tiles x 4 k-quarters)
#pragma unroll
        for (int kt = 0; kt < 4; ++kt) {
            int sw = ((kt * 2 + hi) ^ (q32 & 7)) * 16;
            short8 v0 = *(const short8*)(curV + q32 * 128 + sw);
            short8 v1 = *(const short8*)(curV + (32 + q32) * 128 + sw);
            oa0 = __builtin_amdgcn_mfma_f32_32x32x16_bf16(v0, fr[kt].s8v, oa0, 0, 0, 0);
            oa1 = __builtin_amdgcn_mfma_f32_32x32x16_bf16(v1, fr[kt].s8v, oa1, 0, 0, 0);
        }

        __syncthreads();
    }

    // epilogue: O^T[c][q] -> o[b][q][h*64 + c]
    float inv = 1.f / lrun;
    bf16* op = o + ((long)b * N_SZ + qc * 256 + wv * 32 + q32) * 512 + h * 64;
#pragma unroll
    for (int ct = 0; ct < 2; ++ct) {
#pragma unroll
        for (int rq = 0; rq < 4; ++rq) {
            int c0 = ct * 32 + rq * 8 + hi * 4;
            float v0 = (ct ? oa1[rq * 4 + 0] : oa0[rq * 4 + 0]) * inv;
            float v1 = (ct ? oa1[rq * 4 + 1] : oa0[rq * 4 + 1]) * inv;
            float v2 = (ct ? oa1[rq * 4 + 2] : oa0[rq * 4 + 2]) * inv;
            float v3 = (ct ? oa1[rq * 4 + 3] : oa0[rq * 4 + 3]) * inv;
            uint2 st;
            st.x = cvtpk(v0, v1);
            st.y = cvtpk(v2, v3);
            *(uint2*)(op + c0) = st;
        }
    }
}

extern "C" void kernel_launch(void* const* d_in, const int* in_sizes, int n_in,
                              void* d_out, int out_size, void* d_ws, size_t ws_size,
                              hipStream_t stream) {
    const float* x_q  = (const float*)d_in[0];
    const float* x_kv = (const float*)d_in[1];
    const int*   mask = (const int*)d_in[2];
    const float* Wq   = (const float*)d_in[3];
    const float* Wk   = (const float*)d_in[4];
    const float* Wv   = (const float*)d_in[5];
    const float* Wo   = (const float*)d_in[6];
    const float* bo   = (const float*)d_in[7];
    const float* rpb  = (const float*)d_in[8];
    float* out = (float*)d_out;

    char* w = (char*)d_ws;
    bf16* xq_bf  = (bf16*)(w + 0);           // reused as o_bf after attention
    bf16* xkv_bf = (bf16*)(w + 16777216);
    bf16* WqT    = (bf16*)(w + 50331648);
    bf16* WkT    = WqT + 262144;
    bf16* WvT    = WkT + 262144;
    bf16* WoT    = WvT + 262144;
    bf16* qh     = (bf16*)(w + 52428800);    // [b][h][n][c]
    bf16* kh     = (bf16*)(w + 69206016);    // [b][h][l][c]
    bf16* vTh    = (bf16*)(w + 102760448);   // [b][h][c][l]
    bf16* o_bf   = xq_bf;

    prep<<<25600, 256, 0, stream>>>(x_q, x_kv, xq_bf, xkv_bf,
                                    Wq, Wk, Wv, Wo, WqT, WkT, WvT, WoT);

    gemm_qkv<<<2560, 256, 0, stream>>>(xq_bf, xkv_bf, WqT, WkT, WvT, rpb, qh, kh, vTh);

    attn256<<<512, 512, 0, stream>>>(qh, kh, vTh, mask, o_bf);

    gemm_o<<<512, 256, 0, stream>>>(o_bf, WoT, out, bo);
}